// Round 5
// baseline (131.642 us; speedup 1.0000x reference)
//
#include <hip/hip_runtime.h>

typedef _Float16 half2v __attribute__((ext_vector_type(2)));
typedef _Float16 half8v __attribute__((ext_vector_type(8)));
typedef float f32x4 __attribute__((ext_vector_type(4)));
typedef unsigned uint2v __attribute__((ext_vector_type(2)));

__device__ inline half2v cvt_pk(float a, float b) {
    return __builtin_bit_cast(half2v, __builtin_amdgcn_cvt_pkrtz(a, b));
}
__device__ inline half2v pkmax0(half2v x) {
    half2v r;
    asm("v_pk_max_f16 %0, %1, 0" : "=v"(r) : "v"(x));
    return r;
}
__device__ inline unsigned short f16bits(float f) {
    _Float16 h = (_Float16)f;
    return __builtin_bit_cast(unsigned short, h);
}

// ---------------------------------------------------------------------------
// K0: src/dst = relu(LN(node @ W^T + b)) -> f16; A1 = src@W1a^T + b1 (f32);
//     B1h = dst@W1b^T (f16). Blocks 0..7 also pack w1c / w2 into f16 MFMA
//     A-fragment order; w2 gets the sigma k-permutation:
//       sigma(kt, lq*8+e) = (2*kt + (e>>2))*16 + lq*4 + (e&3)
// ---------------------------------------------------------------------------
__global__ __launch_bounds__(256) void proj_kernel(
    const float* __restrict__ node,
    const float* __restrict__ w_src, const float* __restrict__ b_src,
    const float* __restrict__ g_src, const float* __restrict__ be_src,
    const float* __restrict__ w_dst, const float* __restrict__ b_dst,
    const float* __restrict__ g_dst, const float* __restrict__ be_dst,
    const float* __restrict__ w1, const float* __restrict__ b1,
    const float* __restrict__ w2,
    unsigned short* __restrict__ src_f16, unsigned short* __restrict__ dst_f16,
    float* __restrict__ A1, unsigned short* __restrict__ B1h,
    unsigned short* __restrict__ w1c_frag, unsigned short* __restrict__ w2_frag)
{
    __shared__ float rowbuf[4][64];
    const int wloc = threadIdx.x >> 6;
    const int lane = threadIdx.x & 63;
    const int gw = blockIdx.x * 4 + wloc;     // 0..2047
    const int row = gw & 1023;
    const int kind = gw >> 10;

    const float* W  = kind ? w_dst  : w_src;
    const float* Bv = kind ? b_dst  : b_src;
    const float* G  = kind ? g_dst  : g_src;
    const float* BE = kind ? be_dst : be_src;

    const float* nrow = node + row * 128;
    const float* wrow = W + lane * 128;
    float acA = Bv[lane], acB = 0.f, acC = 0.f, acD = 0.f;
    #pragma unroll 4
    for (int k = 0; k < 128; k += 16) {
        float4 n0 = *(const float4*)(nrow + k);
        float4 w0 = *(const float4*)(wrow + k);
        float4 n1 = *(const float4*)(nrow + k + 4);
        float4 w1v = *(const float4*)(wrow + k + 4);
        float4 n2 = *(const float4*)(nrow + k + 8);
        float4 w2v = *(const float4*)(wrow + k + 8);
        float4 n3 = *(const float4*)(nrow + k + 12);
        float4 w3v = *(const float4*)(wrow + k + 12);
        acA += n0.x * w0.x + n0.y * w0.y + n0.z * w0.z + n0.w * w0.w;
        acB += n1.x * w1v.x + n1.y * w1v.y + n1.z * w1v.z + n1.w * w1v.w;
        acC += n2.x * w2v.x + n2.y * w2v.y + n2.z * w2v.z + n2.w * w2v.w;
        acD += n3.x * w3v.x + n3.y * w3v.y + n3.z * w3v.z + n3.w * w3v.w;
    }
    float acc = (acA + acB) + (acC + acD);
    // LayerNorm over 64 lanes
    float s = acc;
    #pragma unroll
    for (int off = 32; off >= 1; off >>= 1) s += __shfl_xor(s, off);
    float mean = s * (1.0f / 64.0f);
    float d = acc - mean;
    float ss = d * d;
    #pragma unroll
    for (int off = 32; off >= 1; off >>= 1) ss += __shfl_xor(ss, off);
    float rstd = rsqrtf(ss * (1.0f / 64.0f) + 1e-5f);
    float y = fmaxf(d * rstd * G[lane] + BE[lane], 0.0f);

    unsigned short* obf = kind ? dst_f16 : src_f16;
    obf[row * 64 + lane] = f16bits(y);

    rowbuf[wloc][lane] = y;
    __builtin_amdgcn_s_waitcnt(0);
    // A1[row][m] = sum_k y[k]*w1[m][koff+k] (+ b1[m] for src side)
    const int koff = kind * 64;
    float a0 = kind ? 0.0f : b1[lane];
    float a1 = kind ? 0.0f : b1[lane + 64];
    const float* w1r0 = w1 + (size_t)lane * 192 + koff;
    const float* w1r1 = w1 + (size_t)(lane + 64) * 192 + koff;
    #pragma unroll 4
    for (int k = 0; k < 64; k += 4) {
        float4 wa = *(const float4*)(w1r0 + k);
        float4 wb = *(const float4*)(w1r1 + k);
        float y0 = rowbuf[wloc][k], y1 = rowbuf[wloc][k+1];
        float y2 = rowbuf[wloc][k+2], y3 = rowbuf[wloc][k+3];
        a0 += y0*wa.x + y1*wa.y + y2*wa.z + y3*wa.w;
        a1 += y0*wb.x + y1*wb.y + y2*wb.z + y3*wb.w;
    }
    if (kind == 0) {
        A1[row * 128 + lane] = a0;
        A1[row * 128 + lane + 64] = a1;
    } else {
        B1h[row * 128 + lane] = f16bits(a0);
        B1h[row * 128 + lane + 64] = f16bits(a1);
    }

    // ---- weight packing (blocks 0..7 only) ----
    if (blockIdx.x < 8) {
        int t = blockIdx.x * 256 + threadIdx.x;   // 0..2047
        int which = t >> 10;
        int idx = t & 1023;                       // f*64 + l
        int f = idx >> 6, l = idx & 63;
        int lq = l >> 4, lr = l & 15;
        if (which == 0) {
            int mt = f >> 1, kt = f & 1;          // A-frag of W1c
            #pragma unroll
            for (int e = 0; e < 8; e++)
                w1c_frag[idx * 8 + e] =
                    f16bits(w1[(size_t)(mt * 16 + lr) * 192 + 128 + kt * 32 + lq * 8 + e]);
        } else {
            int mt2 = f >> 2, kt2 = f & 3;        // A-frag of W2 with sigma permutation
            #pragma unroll
            for (int e = 0; e < 8; e++) {
                int col = (2 * kt2 + (e >> 2)) * 16 + lq * 4 + (e & 3);
                w2_frag[idx * 8 + e] =
                    f16bits(w2[(size_t)(mt2 * 16 + lr) * 128 + col]);
            }
        }
    }
}

// ---------------------------------------------------------------------------
// K1: pairwise MLP. 512 threads = 8 waves; block tile 32 i x 64 j.
// Wave (iw = wv&3, wh = wv>>2): i in [i0+iw*8, +8), j in [j0+wh*32, +32).
// 16 chunks/wave, software-pipelined: package (src,dst,A1-Cinit) for chunk
// c+1 prefetched while chunk c computes. No LDS, no barriers.
// ---------------------------------------------------------------------------
#define PKG(ACC, S0, S1, D0, D1, C) do {                                        \
    const int ip_ = ibase + ((C) >> 1);                                         \
    const int jp_ = jbase + (((C) & 1) << 4) + lr;                              \
    const uint4* sr_ = (const uint4*)(src_f16 + (size_t)ip_ * 64);              \
    S0 = __builtin_bit_cast(half8v, sr_[lq]);                                   \
    S1 = __builtin_bit_cast(half8v, sr_[4 + lq]);                               \
    const uint4* dr_ = (const uint4*)(dst_f16 + (size_t)jp_ * 64);              \
    D0 = __builtin_bit_cast(half8v, dr_[lq]);                                   \
    D1 = __builtin_bit_cast(half8v, dr_[4 + lq]);                               \
    _Pragma("unroll")                                                           \
    for (int mt_ = 0; mt_ < 8; mt_++)                                           \
        ACC[mt_] = *(const f32x4*)(A1 + (size_t)ip_ * 128 + mt_ * 16 + lq * 4); \
} while (0)

#define COMPUTE(ACC, S0, S1, D0, D1, C) do {                                    \
    const int i_ = ibase + ((C) >> 1);                                          \
    const int jc_ = jbase + (((C) & 1) << 4);                                   \
    const int j_ = jc_ + lr;                                                    \
    /* b1 rows for this j (needed at epilogue; issue early) */                  \
    half2v b1pk_[8][2];                                                         \
    _Pragma("unroll")                                                           \
    for (int mt_ = 0; mt_ < 8; mt_++) {                                         \
        uint2v bl_ = *(const uint2v*)(B1h + (size_t)j_ * 128 + mt_ * 16 + lq * 4); \
        b1pk_[mt_][0] = __builtin_bit_cast(half2v, bl_[0]);                     \
        b1pk_[mt_][1] = __builtin_bit_cast(half2v, bl_[1]);                     \
    }                                                                           \
    const half8v c0_ = S0 * D0;                                                 \
    const half8v c1_ = S1 * D1;                                                 \
    _Pragma("unroll")                                                           \
    for (int mt_ = 0; mt_ < 8; mt_++) {                                         \
        ACC[mt_] = __builtin_amdgcn_mfma_f32_16x16x32_f16(w1f[mt_][0], c0_, ACC[mt_], 0, 0, 0); \
        ACC[mt_] = __builtin_amdgcn_mfma_f32_16x16x32_f16(w1f[mt_][1], c1_, ACC[mt_], 0, 0, 0); \
    }                                                                           \
    unsigned P_[16];                                                            \
    _Pragma("unroll")                                                           \
    for (int mt_ = 0; mt_ < 8; mt_++) {                                         \
        half2v p0_ = cvt_pk(ACC[mt_][0], ACC[mt_][1]) + b1pk_[mt_][0];          \
        half2v p1_ = cvt_pk(ACC[mt_][2], ACC[mt_][3]) + b1pk_[mt_][1];          \
        P_[mt_ * 2 + 0] = __builtin_bit_cast(unsigned, pkmax0(p0_));            \
        P_[mt_ * 2 + 1] = __builtin_bit_cast(unsigned, pkmax0(p1_));            \
    }                                                                           \
    f32x4 acc2_[4];                                                             \
    {                                                                           \
        uint4 hb_ = {P_[0], P_[1], P_[2], P_[3]};                               \
        half8v hf_ = __builtin_bit_cast(half8v, hb_);                           \
        _Pragma("unroll")                                                       \
        for (int mt2_ = 0; mt2_ < 4; mt2_++)                                    \
            acc2_[mt2_] = __builtin_amdgcn_mfma_f32_16x16x32_f16(w2f[mt2_][0], hf_, b2v[mt2_], 0, 0, 0); \
    }                                                                           \
    _Pragma("unroll")                                                           \
    for (int kt_ = 1; kt_ < 4; kt_++) {                                         \
        uint4 hb_ = {P_[4 * kt_], P_[4 * kt_ + 1], P_[4 * kt_ + 2], P_[4 * kt_ + 3]}; \
        half8v hf_ = __builtin_bit_cast(half8v, hb_);                           \
        _Pragma("unroll")                                                       \
        for (int mt2_ = 0; mt2_ < 4; mt2_++)                                    \
            acc2_[mt2_] = __builtin_amdgcn_mfma_f32_16x16x32_f16(w2f[mt2_][kt_], hf_, acc2_[mt2_], 0, 0, 0); \
    }                                                                           \
    float part_ = 0.0f;                                                         \
    _Pragma("unroll")                                                           \
    for (int mt2_ = 0; mt2_ < 4; mt2_++)                                        \
        _Pragma("unroll")                                                       \
        for (int r_ = 0; r_ < 4; r_++)                                          \
            part_ += fmaxf(acc2_[mt2_][r_], 0.0f) * w3v[mt2_][r_];              \
    part_ += __shfl_xor(part_, 16);                                             \
    part_ += __shfl_xor(part_, 32);                                             \
    if (lane < 16)                                                              \
        out[(size_t)i_ * 1024 + jc_ + lane] = part_ + b3v;                      \
} while (0)

__global__ __launch_bounds__(512, 2) void pair_kernel(
    const unsigned short* __restrict__ src_f16, const unsigned short* __restrict__ dst_f16,
    const float* __restrict__ A1, const unsigned short* __restrict__ B1h,
    const unsigned short* __restrict__ w1c_frag, const unsigned short* __restrict__ w2_frag,
    const float* __restrict__ b2, const float* __restrict__ w3,
    const float* __restrict__ b3, float* __restrict__ out)
{
    const int tid = threadIdx.x;
    const int wv = tid >> 6;
    const int lane = tid & 63;
    const int lq = lane >> 4, lr = lane & 15;
    const int i0 = blockIdx.y * 32, j0 = blockIdx.x * 64;
    const int ibase = i0 + (wv & 3) * 8;
    const int jbase = j0 + (wv >> 2) * 32;

    // ---- weight fragments straight from global (coalesced b128, L2-hot) ----
    half8v w1f[8][2], w2f[4][4];
    {
        const uint4* gw1 = (const uint4*)w1c_frag;
        #pragma unroll
        for (int mt = 0; mt < 8; mt++)
            #pragma unroll
            for (int kt = 0; kt < 2; kt++)
                w1f[mt][kt] = __builtin_bit_cast(half8v, gw1[(mt * 2 + kt) * 64 + lane]);
        const uint4* gw2 = (const uint4*)w2_frag;
        #pragma unroll
        for (int mt2 = 0; mt2 < 4; mt2++)
            #pragma unroll
            for (int kt = 0; kt < 4; kt++)
                w2f[mt2][kt] = __builtin_bit_cast(half8v, gw2[(mt2 * 4 + kt) * 64 + lane]);
    }
    f32x4 b2v[4], w3v[4];
    #pragma unroll
    for (int mt2 = 0; mt2 < 4; mt2++) {
        b2v[mt2] = *(const f32x4*)(b2 + mt2 * 16 + lq * 4);
        w3v[mt2] = *(const f32x4*)(w3 + mt2 * 16 + lq * 4);
    }
    const float b3v = b3[0];

    // ---- software-pipelined chunk loop (16 chunks, 2-unrolled) ----
    f32x4 accA[8], accB[8];
    half8v sA0, sA1, dA0, dA1, sB0, sB1, dB0, dB1;

    PKG(accA, sA0, sA1, dA0, dA1, 0);
    for (int c = 0; c < 16; c += 2) {
        PKG(accB, sB0, sB1, dB0, dB1, c + 1);
        COMPUTE(accA, sA0, sA1, dA0, dA1, c);
        if (c + 2 < 16) PKG(accA, sA0, sA1, dA0, dA1, c + 2);
        COMPUTE(accB, sB0, sB1, dB0, dB1, c + 1);
    }
}

// ---------------------------------------------------------------------------
extern "C" void kernel_launch(void* const* d_in, const int* in_sizes, int n_in,
                              void* d_out, int out_size, void* d_ws, size_t ws_size,
                              hipStream_t stream) {
    (void)in_sizes; (void)n_in; (void)out_size; (void)ws_size;
    const float* node   = (const float*)d_in[0];
    const float* w_src  = (const float*)d_in[1];
    const float* b_src  = (const float*)d_in[2];
    const float* g_src  = (const float*)d_in[3];
    const float* be_src = (const float*)d_in[4];
    const float* w_dst  = (const float*)d_in[5];
    const float* b_dst  = (const float*)d_in[6];
    const float* g_dst  = (const float*)d_in[7];
    const float* be_dst = (const float*)d_in[8];
    const float* w1     = (const float*)d_in[9];
    const float* b1     = (const float*)d_in[10];
    const float* w2     = (const float*)d_in[11];
    const float* b2     = (const float*)d_in[12];
    const float* w3     = (const float*)d_in[13];
    const float* b3     = (const float*)d_in[14];

    char* ws = (char*)d_ws;
    unsigned short* src_f16  = (unsigned short*)(ws);
    unsigned short* dst_f16  = (unsigned short*)(ws + 131072);
    float*          A1       = (float*)(ws + 262144);
    unsigned short* B1h      = (unsigned short*)(ws + 786432);
    unsigned short* w1c_frag = (unsigned short*)(ws + 1310720);
    unsigned short* w2_frag  = (unsigned short*)(ws + 1327104);

    hipLaunchKernelGGL(proj_kernel, dim3(512), dim3(256), 0, stream,
                       node, w_src, b_src, g_src, be_src, w_dst, b_dst, g_dst, be_dst,
                       w1, b1, w2, src_f16, dst_f16, A1, B1h, w1c_frag, w2_frag);
    hipLaunchKernelGGL(pair_kernel, dim3(16, 32), dim3(512), 0, stream,
                       src_f16, dst_f16, A1, B1h, w1c_frag, w2_frag, b2, w3, b3,
                       (float*)d_out);
}

// Round 6
// 63.688 us; speedup vs baseline: 2.0670x; 2.0670x over previous
//
#include <hip/hip_runtime.h>

typedef _Float16 half2v __attribute__((ext_vector_type(2)));
typedef _Float16 half8v __attribute__((ext_vector_type(8)));
typedef float f32x4 __attribute__((ext_vector_type(4)));
typedef unsigned uint2v __attribute__((ext_vector_type(2)));

__device__ inline half2v cvt_pk(float a, float b) {
    return __builtin_bit_cast(half2v, __builtin_amdgcn_cvt_pkrtz(a, b));
}
__device__ inline half2v pkmax0(half2v x) {
    half2v r;
    asm("v_pk_max_f16 %0, %1, 0" : "=v"(r) : "v"(x));
    return r;
}
__device__ inline unsigned short f16bits(float f) {
    _Float16 h = (_Float16)f;
    return __builtin_bit_cast(unsigned short, h);
}

// ---------------------------------------------------------------------------
// K0: src/dst = relu(LN(node @ W^T + b)) -> f16; A1 = src@W1a^T + b1 (f32);
//     B1h = dst@W1b^T (f16). Blocks 0..7 pack w1c / w2 into f16 MFMA
//     A-fragment order (w2 with sigma k-permutation); block 8 packs w3 with
//     the same sigma so GEMM3's B-operand is the lane's own acc2 registers.
//       sigma(kt, lq*8+e) = (2*kt + (e>>2))*16 + lq*4 + (e&3)
// ---------------------------------------------------------------------------
__global__ __launch_bounds__(256) void proj_kernel(
    const float* __restrict__ node,
    const float* __restrict__ w_src, const float* __restrict__ b_src,
    const float* __restrict__ g_src, const float* __restrict__ be_src,
    const float* __restrict__ w_dst, const float* __restrict__ b_dst,
    const float* __restrict__ g_dst, const float* __restrict__ be_dst,
    const float* __restrict__ w1, const float* __restrict__ b1,
    const float* __restrict__ w2, const float* __restrict__ w3,
    unsigned short* __restrict__ src_f16, unsigned short* __restrict__ dst_f16,
    float* __restrict__ A1, unsigned short* __restrict__ B1h,
    unsigned short* __restrict__ w1c_frag, unsigned short* __restrict__ w2_frag,
    unsigned short* __restrict__ w3p)
{
    __shared__ float rowbuf[4][64];
    const int wloc = threadIdx.x >> 6;
    const int lane = threadIdx.x & 63;
    const int gw = blockIdx.x * 4 + wloc;     // 0..2047
    const int row = gw & 1023;
    const int kind = gw >> 10;

    const float* W  = kind ? w_dst  : w_src;
    const float* Bv = kind ? b_dst  : b_src;
    const float* G  = kind ? g_dst  : g_src;
    const float* BE = kind ? be_dst : be_src;

    const float* nrow = node + row * 128;
    const float* wrow = W + lane * 128;
    float acA = Bv[lane], acB = 0.f, acC = 0.f, acD = 0.f;
    #pragma unroll 4
    for (int k = 0; k < 128; k += 16) {
        float4 n0 = *(const float4*)(nrow + k);
        float4 w0 = *(const float4*)(wrow + k);
        float4 n1 = *(const float4*)(nrow + k + 4);
        float4 w1v = *(const float4*)(wrow + k + 4);
        float4 n2 = *(const float4*)(nrow + k + 8);
        float4 w2v = *(const float4*)(wrow + k + 8);
        float4 n3 = *(const float4*)(nrow + k + 12);
        float4 w3v = *(const float4*)(wrow + k + 12);
        acA += n0.x * w0.x + n0.y * w0.y + n0.z * w0.z + n0.w * w0.w;
        acB += n1.x * w1v.x + n1.y * w1v.y + n1.z * w1v.z + n1.w * w1v.w;
        acC += n2.x * w2v.x + n2.y * w2v.y + n2.z * w2v.z + n2.w * w2v.w;
        acD += n3.x * w3v.x + n3.y * w3v.y + n3.z * w3v.z + n3.w * w3v.w;
    }
    float acc = (acA + acB) + (acC + acD);
    // LayerNorm over 64 lanes
    float s = acc;
    #pragma unroll
    for (int off = 32; off >= 1; off >>= 1) s += __shfl_xor(s, off);
    float mean = s * (1.0f / 64.0f);
    float d = acc - mean;
    float ss = d * d;
    #pragma unroll
    for (int off = 32; off >= 1; off >>= 1) ss += __shfl_xor(ss, off);
    float rstd = rsqrtf(ss * (1.0f / 64.0f) + 1e-5f);
    float y = fmaxf(d * rstd * G[lane] + BE[lane], 0.0f);

    unsigned short* obf = kind ? dst_f16 : src_f16;
    obf[row * 64 + lane] = f16bits(y);

    rowbuf[wloc][lane] = y;
    __builtin_amdgcn_s_waitcnt(0);
    // A1[row][m] = sum_k y[k]*w1[m][koff+k] (+ b1[m] for src side)
    const int koff = kind * 64;
    float a0 = kind ? 0.0f : b1[lane];
    float a1 = kind ? 0.0f : b1[lane + 64];
    const float* w1r0 = w1 + (size_t)lane * 192 + koff;
    const float* w1r1 = w1 + (size_t)(lane + 64) * 192 + koff;
    #pragma unroll 4
    for (int k = 0; k < 64; k += 4) {
        float4 wa = *(const float4*)(w1r0 + k);
        float4 wb = *(const float4*)(w1r1 + k);
        float y0 = rowbuf[wloc][k], y1 = rowbuf[wloc][k+1];
        float y2 = rowbuf[wloc][k+2], y3 = rowbuf[wloc][k+3];
        a0 += y0*wa.x + y1*wa.y + y2*wa.z + y3*wa.w;
        a1 += y0*wb.x + y1*wb.y + y2*wb.z + y3*wb.w;
    }
    if (kind == 0) {
        A1[row * 128 + lane] = a0;
        A1[row * 128 + lane + 64] = a1;
    } else {
        B1h[row * 128 + lane] = f16bits(a0);
        B1h[row * 128 + lane + 64] = f16bits(a1);
    }

    // ---- weight packing (blocks 0..8 only) ----
    if (blockIdx.x < 8) {
        int t = blockIdx.x * 256 + threadIdx.x;   // 0..2047
        int which = t >> 10;
        int idx = t & 1023;                       // f*64 + l
        int f = idx >> 6, l = idx & 63;
        int lq = l >> 4, lr = l & 15;
        if (which == 0) {
            int mt = f >> 1, kt = f & 1;          // A-frag of W1c
            #pragma unroll
            for (int e = 0; e < 8; e++)
                w1c_frag[idx * 8 + e] =
                    f16bits(w1[(size_t)(mt * 16 + lr) * 192 + 128 + kt * 32 + lq * 8 + e]);
        } else {
            int mt2 = f >> 2, kt2 = f & 3;        // A-frag of W2 with sigma permutation
            #pragma unroll
            for (int e = 0; e < 8; e++) {
                int col = (2 * kt2 + (e >> 2)) * 16 + lq * 4 + (e & 3);
                w2_frag[idx * 8 + e] =
                    f16bits(w2[(size_t)(mt2 * 16 + lr) * 128 + col]);
            }
        }
    } else if (blockIdx.x == 8 && threadIdx.x < 64) {
        // w3 packed with sigma: slot (kt, lq, e) <- w3[(2kt+(e>>2))*16 + lq*4 + (e&3)]
        int l = threadIdx.x;
        int kt = l >> 5, rem = l & 31, lqq = rem >> 3, ee = rem & 7;
        w3p[l] = f16bits(w3[(2 * kt + (ee >> 2)) * 16 + lqq * 4 + (ee & 3)]);
    }
}

// ---------------------------------------------------------------------------
// K1: pairwise MLP, all-register MFMA, loop-inverted so the j-side package
// (dst frags + B1h) is loaded once per wave.
// Block = 32 i x 32 j, 4 waves; wave (wv&1, wv>>1) owns 16 i x 16 j.
// Chunk = (one i, 16 j = lr). GEMM1: W1c(A) x cross^T(B), C-init = A1[i].
// Epilogue: +B1h, relu, pack -> P[16]. GEMM2: sigma-W2, C-init = b2.
// GEMM3: sigma-w3 MFMA, C-init = b3. Store row of 16.
// ---------------------------------------------------------------------------
__global__ __launch_bounds__(256, 2) void pair_kernel(
    const unsigned short* __restrict__ src_f16, const unsigned short* __restrict__ dst_f16,
    const float* __restrict__ A1, const unsigned short* __restrict__ B1h,
    const unsigned short* __restrict__ w1c_frag, const unsigned short* __restrict__ w2_frag,
    const unsigned short* __restrict__ w3p, const float* __restrict__ b2,
    const float* __restrict__ b3, float* __restrict__ out)
{
    const int tid = threadIdx.x;
    const int wv = tid >> 6;
    const int lane = tid & 63;
    const int lq = lane >> 4, lr = lane & 15;
    const int i0 = blockIdx.y * 32, j0 = blockIdx.x * 32;
    const int ibase = i0 + (wv & 1) * 16;
    const int jbase = j0 + (wv >> 1) * 16;

    // ---- weight fragments straight from global (coalesced b128, L2-hot) ----
    half8v w1f[8][2], w2f[4][4], w3f[2];
    {
        const uint4* gw1 = (const uint4*)w1c_frag;
        #pragma unroll
        for (int mt = 0; mt < 8; mt++)
            #pragma unroll
            for (int kt = 0; kt < 2; kt++)
                w1f[mt][kt] = __builtin_bit_cast(half8v, gw1[(mt * 2 + kt) * 64 + lane]);
        const uint4* gw2 = (const uint4*)w2_frag;
        #pragma unroll
        for (int mt2 = 0; mt2 < 4; mt2++)
            #pragma unroll
            for (int kt = 0; kt < 4; kt++)
                w2f[mt2][kt] = __builtin_bit_cast(half8v, gw2[(mt2 * 4 + kt) * 64 + lane]);
        #pragma unroll
        for (int kt = 0; kt < 2; kt++)
            w3f[kt] = *(const half8v*)(w3p + kt * 32 + lq * 8);
    }
    f32x4 b2v[4];
    #pragma unroll
    for (int mt2 = 0; mt2 < 4; mt2++)
        b2v[mt2] = *(const f32x4*)(b2 + mt2 * 16 + lq * 4);
    const float b3s = b3[0];
    const f32x4 b3c = {b3s, b3s, b3s, b3s};

    // ---- j-side package: loaded once per wave ----
    const int j = jbase + lr;
    const uint4* drow = (const uint4*)(dst_f16 + (size_t)j * 64);
    const half8v dstf0 = __builtin_bit_cast(half8v, drow[lq]);
    const half8v dstf1 = __builtin_bit_cast(half8v, drow[4 + lq]);
    half2v b1pk[8][2];
    #pragma unroll
    for (int mt = 0; mt < 8; mt++) {
        uint2v bl = *(const uint2v*)(B1h + (size_t)j * 128 + mt * 16 + lq * 4);
        b1pk[mt][0] = __builtin_bit_cast(half2v, bl[0]);
        b1pk[mt][1] = __builtin_bit_cast(half2v, bl[1]);
    }

    // ---- 16 chunks: one i each ----
    for (int cc = 0; cc < 16; cc++) {
        const int i = ibase + cc;
        // src slices (broadcast) + A1 C-init (broadcast)
        const uint4* srow = (const uint4*)(src_f16 + (size_t)i * 64);
        const half8v s0 = __builtin_bit_cast(half8v, srow[lq]);
        const half8v s1 = __builtin_bit_cast(half8v, srow[4 + lq]);
        f32x4 acc1[8];
        #pragma unroll
        for (int mt = 0; mt < 8; mt++)
            acc1[mt] = *(const f32x4*)(A1 + (size_t)i * 128 + mt * 16 + lq * 4);
        // cross features
        const half8v c0 = s0 * dstf0;
        const half8v c1 = s1 * dstf1;
        // GEMM1
        #pragma unroll
        for (int mt = 0; mt < 8; mt++) {
            acc1[mt] = __builtin_amdgcn_mfma_f32_16x16x32_f16(w1f[mt][0], c0, acc1[mt], 0, 0, 0);
            acc1[mt] = __builtin_amdgcn_mfma_f32_16x16x32_f16(w1f[mt][1], c1, acc1[mt], 0, 0, 0);
        }
        // epilogue: +B1, relu, pack f16 into P
        unsigned P[16];
        #pragma unroll
        for (int mt = 0; mt < 8; mt++) {
            half2v p0 = cvt_pk(acc1[mt][0], acc1[mt][1]) + b1pk[mt][0];
            half2v p1 = cvt_pk(acc1[mt][2], acc1[mt][3]) + b1pk[mt][1];
            P[mt * 2 + 0] = __builtin_bit_cast(unsigned, pkmax0(p0));
            P[mt * 2 + 1] = __builtin_bit_cast(unsigned, pkmax0(p1));
        }
        // GEMM2: sigma-W2; B-frag = own P regs; C-init = b2
        f32x4 acc2[4];
        {
            uint4 hb = {P[0], P[1], P[2], P[3]};
            half8v hf = __builtin_bit_cast(half8v, hb);
            #pragma unroll
            for (int mt2 = 0; mt2 < 4; mt2++)
                acc2[mt2] = __builtin_amdgcn_mfma_f32_16x16x32_f16(w2f[mt2][0], hf, b2v[mt2], 0, 0, 0);
        }
        #pragma unroll
        for (int kt = 1; kt < 4; kt++) {
            uint4 hb = {P[4 * kt], P[4 * kt + 1], P[4 * kt + 2], P[4 * kt + 3]};
            half8v hf = __builtin_bit_cast(half8v, hb);
            #pragma unroll
            for (int mt2 = 0; mt2 < 4; mt2++)
                acc2[mt2] = __builtin_amdgcn_mfma_f32_16x16x32_f16(w2f[mt2][kt], hf, acc2[mt2], 0, 0, 0);
        }
        // GEMM3: relu(h2) -> f16 (sigma order), 2 MFMAs, C-init = b3
        unsigned P2[8];
        #pragma unroll
        for (int mt2 = 0; mt2 < 4; mt2++) {
            P2[mt2 * 2 + 0] = __builtin_bit_cast(unsigned, pkmax0(cvt_pk(acc2[mt2][0], acc2[mt2][1])));
            P2[mt2 * 2 + 1] = __builtin_bit_cast(unsigned, pkmax0(cvt_pk(acc2[mt2][2], acc2[mt2][3])));
        }
        uint4 h20 = {P2[0], P2[1], P2[2], P2[3]};
        uint4 h21 = {P2[4], P2[5], P2[6], P2[7]};
        f32x4 acc3 = __builtin_amdgcn_mfma_f32_16x16x32_f16(
            w3f[0], __builtin_bit_cast(half8v, h20), b3c, 0, 0, 0);
        acc3 = __builtin_amdgcn_mfma_f32_16x16x32_f16(
            w3f[1], __builtin_bit_cast(half8v, h21), acc3, 0, 0, 0);
        if (lane < 16)
            out[(size_t)i * 1024 + jbase + lane] = acc3[0];
    }
}

// ---------------------------------------------------------------------------
extern "C" void kernel_launch(void* const* d_in, const int* in_sizes, int n_in,
                              void* d_out, int out_size, void* d_ws, size_t ws_size,
                              hipStream_t stream) {
    (void)in_sizes; (void)n_in; (void)out_size; (void)ws_size;
    const float* node   = (const float*)d_in[0];
    const float* w_src  = (const float*)d_in[1];
    const float* b_src  = (const float*)d_in[2];
    const float* g_src  = (const float*)d_in[3];
    const float* be_src = (const float*)d_in[4];
    const float* w_dst  = (const float*)d_in[5];
    const float* b_dst  = (const float*)d_in[6];
    const float* g_dst  = (const float*)d_in[7];
    const float* be_dst = (const float*)d_in[8];
    const float* w1     = (const float*)d_in[9];
    const float* b1     = (const float*)d_in[10];
    const float* w2     = (const float*)d_in[11];
    const float* b2     = (const float*)d_in[12];
    const float* w3     = (const float*)d_in[13];
    const float* b3     = (const float*)d_in[14];

    char* ws = (char*)d_ws;
    unsigned short* src_f16  = (unsigned short*)(ws);
    unsigned short* dst_f16  = (unsigned short*)(ws + 131072);
    float*          A1       = (float*)(ws + 262144);
    unsigned short* B1h      = (unsigned short*)(ws + 786432);
    unsigned short* w1c_frag = (unsigned short*)(ws + 1310720);
    unsigned short* w2_frag  = (unsigned short*)(ws + 1327104);
    unsigned short* w3p      = (unsigned short*)(ws + 1343488);

    hipLaunchKernelGGL(proj_kernel, dim3(512), dim3(256), 0, stream,
                       node, w_src, b_src, g_src, be_src, w_dst, b_dst, g_dst, be_dst,
                       w1, b1, w2, w3, src_f16, dst_f16, A1, B1h,
                       w1c_frag, w2_frag, w3p);
    hipLaunchKernelGGL(pair_kernel, dim3(32, 32), dim3(256), 0, stream,
                       src_f16, dst_f16, A1, B1h, w1c_frag, w2_frag, w3p, b2, b3,
                       (float*)d_out);
}

// Round 7
// 57.169 us; speedup vs baseline: 2.3027x; 1.1140x over previous
//
#include <hip/hip_runtime.h>

typedef _Float16 half2v __attribute__((ext_vector_type(2)));
typedef _Float16 half8v __attribute__((ext_vector_type(8)));
typedef float f32x4 __attribute__((ext_vector_type(4)));
typedef unsigned uint2v __attribute__((ext_vector_type(2)));

__device__ inline half2v cvt_pk(float a, float b) {
    return __builtin_bit_cast(half2v, __builtin_amdgcn_cvt_pkrtz(a, b));
}
__device__ inline half2v pkmax0(half2v x) {
    half2v r;
    asm("v_pk_max_f16 %0, %1, 0" : "=v"(r) : "v"(x));
    return r;
}
__device__ inline unsigned short f16bits(float f) {
    _Float16 h = (_Float16)f;
    return __builtin_bit_cast(unsigned short, h);
}
__device__ inline unsigned packf16(float a, float b) {
    return (unsigned)f16bits(a) | ((unsigned)f16bits(b) << 16);
}
__device__ inline float lo16(unsigned u) {
    return (float)__builtin_bit_cast(_Float16, (unsigned short)(u & 0xffffu));
}
__device__ inline float hi16(unsigned u) {
    return (float)__builtin_bit_cast(_Float16, (unsigned short)(u >> 16));
}

// ---------------------------------------------------------------------------
// K0: src/dst = relu(LN(node @ W^T + b)) -> f16; A1 = src@W1a^T + b1 (f32);
//     B1h = dst@W1b^T (f16). W and the w1 k-slice are staged into LDS as f16
//     with conflict-free strides (65 / 33 dwords -> bank = (lane + k) % 32).
//     Blocks 0..7 pack w1c/w2 into MFMA A-frag order (w2 with sigma perm);
//     block 8 packs w3 with sigma.
//       sigma(kt, lq*8+e) = (2*kt + (e>>2))*16 + lq*4 + (e&3)
// ---------------------------------------------------------------------------
__global__ __launch_bounds__(256) void proj_kernel(
    const float* __restrict__ node,
    const float* __restrict__ w_src, const float* __restrict__ b_src,
    const float* __restrict__ g_src, const float* __restrict__ be_src,
    const float* __restrict__ w_dst, const float* __restrict__ b_dst,
    const float* __restrict__ g_dst, const float* __restrict__ be_dst,
    const float* __restrict__ w1, const float* __restrict__ b1,
    const float* __restrict__ w2, const float* __restrict__ w3,
    unsigned short* __restrict__ src_f16, unsigned short* __restrict__ dst_f16,
    float* __restrict__ A1, unsigned short* __restrict__ B1h,
    unsigned short* __restrict__ w1c_frag, unsigned short* __restrict__ w2_frag,
    unsigned short* __restrict__ w3p)
{
    __shared__ unsigned sWh[64 * 65];    // W(kind) as packed f16 pairs, stride 65
    __shared__ unsigned sw1h[128 * 33];  // w1[:,koff:koff+64] f16 pairs, stride 33
    __shared__ float snode[4][128];
    __shared__ float sy[4][64];

    const int tid = threadIdx.x;
    const int wloc = tid >> 6;
    const int lane = tid & 63;
    const int gw = blockIdx.x * 4 + wloc;     // 0..2047
    const int row = gw & 1023;
    const int kind = gw >> 10;                // uniform per block

    const float* W  = kind ? w_dst  : w_src;
    const float* Bv = kind ? b_dst  : b_src;
    const float* G  = kind ? g_dst  : g_src;
    const float* BE = kind ? be_dst : be_src;
    const int koff = kind * 64;

    // ---- stage W (64x128) and w1-slice (128x64) as f16 pairs, coalesced ----
    #pragma unroll
    for (int u = 0; u < 16; u++) {
        int w = u * 256 + tid;                // 0..4095
        int r = w >> 6, c2 = w & 63;
        float2 v = *(const float2*)(W + r * 128 + c2 * 2);
        sWh[r * 65 + c2] = packf16(v.x, v.y);
    }
    #pragma unroll
    for (int u = 0; u < 16; u++) {
        int w = u * 256 + tid;                // 0..4095
        int r = w >> 5, c2 = w & 31;
        float2 v = *(const float2*)(w1 + (size_t)r * 192 + koff + c2 * 2);
        sw1h[r * 33 + c2] = packf16(v.x, v.y);
    }
    // stage node row (per wave, coalesced)
    snode[wloc][lane]      = node[row * 128 + lane];
    snode[wloc][lane + 64] = node[row * 128 + 64 + lane];
    __syncthreads();

    // ---- projection dot: acc = b + node . W[lane,:] ----
    float acc = Bv[lane];
    #pragma unroll 8
    for (int k2 = 0; k2 < 64; k2++) {
        unsigned wp = sWh[lane * 65 + k2];
        float2 nv = *(const float2*)&snode[wloc][2 * k2];
        acc += nv.x * lo16(wp) + nv.y * hi16(wp);
    }

    // LayerNorm over 64 lanes
    float s = acc;
    #pragma unroll
    for (int off = 32; off >= 1; off >>= 1) s += __shfl_xor(s, off);
    float mean = s * (1.0f / 64.0f);
    float d = acc - mean;
    float ss = d * d;
    #pragma unroll
    for (int off = 32; off >= 1; off >>= 1) ss += __shfl_xor(ss, off);
    float rstd = rsqrtf(ss * (1.0f / 64.0f) + 1e-5f);
    float y = fmaxf(d * rstd * G[lane] + BE[lane], 0.0f);

    unsigned short* obf = kind ? dst_f16 : src_f16;
    obf[row * 64 + lane] = f16bits(y);

    sy[wloc][lane] = y;
    __builtin_amdgcn_s_waitcnt(0);   // within-wave LDS RAW

    // ---- A1/B1 projection: a{0,1} = y . w1[m, koff:koff+64] ----
    float a0 = kind ? 0.0f : b1[lane];
    float a1 = kind ? 0.0f : b1[lane + 64];
    #pragma unroll 8
    for (int k2 = 0; k2 < 32; k2++) {
        float2 yv = *(const float2*)&sy[wloc][2 * k2];
        unsigned wa = sw1h[lane * 33 + k2];
        unsigned wb = sw1h[(lane + 64) * 33 + k2];
        a0 += yv.x * lo16(wa) + yv.y * hi16(wa);
        a1 += yv.x * lo16(wb) + yv.y * hi16(wb);
    }
    if (kind == 0) {
        A1[row * 128 + lane] = a0;
        A1[row * 128 + lane + 64] = a1;
    } else {
        B1h[row * 128 + lane] = f16bits(a0);
        B1h[row * 128 + lane + 64] = f16bits(a1);
    }

    // ---- weight packing (blocks 0..8 only) ----
    if (blockIdx.x < 8) {
        int t = blockIdx.x * 256 + threadIdx.x;   // 0..2047
        int which = t >> 10;
        int idx = t & 1023;                       // f*64 + l
        int f = idx >> 6, l = idx & 63;
        int lqq = l >> 4, lrr = l & 15;
        if (which == 0) {
            int mt = f >> 1, kt = f & 1;          // A-frag of W1c
            #pragma unroll
            for (int e = 0; e < 8; e++)
                w1c_frag[idx * 8 + e] =
                    f16bits(w1[(size_t)(mt * 16 + lrr) * 192 + 128 + kt * 32 + lqq * 8 + e]);
        } else {
            int mt2 = f >> 2, kt2 = f & 3;        // A-frag of W2 with sigma perm
            #pragma unroll
            for (int e = 0; e < 8; e++) {
                int col = (2 * kt2 + (e >> 2)) * 16 + lqq * 4 + (e & 3);
                w2_frag[idx * 8 + e] =
                    f16bits(w2[(size_t)(mt2 * 16 + lrr) * 128 + col]);
            }
        }
    } else if (blockIdx.x == 8 && threadIdx.x < 64) {
        int l = threadIdx.x;
        int kt = l >> 5, rem = l & 31, lqq = rem >> 3, ee = rem & 7;
        w3p[l] = f16bits(w3[(2 * kt + (ee >> 2)) * 16 + lqq * 4 + (ee & 3)]);
    }
}

// ---------------------------------------------------------------------------
// K1: pairwise MLP, all-register MFMA. Persistent regs (weights, j-package)
// are PINNED with empty asm so the compiler cannot rematerialize their loads
// inside the chunk loop (R6: VGPR=108 < 128 regs of weights => remat'd).
// Phase order per chunk keeps peak live regs ~250:
//   cross -> G1(mt0-3) -> epiA -> G2(kt0,1) -> G1(mt4-7) -> epiB
//   -> prefetch(next src+A1) -> G2(kt2,3) -> G3 -> store
// ---------------------------------------------------------------------------
#define PIN(x) asm volatile("" : "+v"(x))

__global__ __launch_bounds__(256, 2) void pair_kernel(
    const unsigned short* __restrict__ src_f16, const unsigned short* __restrict__ dst_f16,
    const float* __restrict__ A1, const unsigned short* __restrict__ B1h,
    const unsigned short* __restrict__ w1c_frag, const unsigned short* __restrict__ w2_frag,
    const unsigned short* __restrict__ w3p, const float* __restrict__ b2,
    const float* __restrict__ b3, float* __restrict__ out)
{
    const int tid = threadIdx.x;
    const int wv = tid >> 6;
    const int lane = tid & 63;
    const int lq = lane >> 4, lr = lane & 15;
    const int i0 = blockIdx.y * 32, j0 = blockIdx.x * 32;
    const int ibase = i0 + (wv & 1) * 16;
    const int jbase = j0 + (wv >> 1) * 16;

    // ---- persistent register state (pinned) ----
    half8v w1f[8][2], w2f[4][4], w3f[2];
    {
        const uint4* gw1 = (const uint4*)w1c_frag;
        #pragma unroll
        for (int mt = 0; mt < 8; mt++)
            #pragma unroll
            for (int kt = 0; kt < 2; kt++) {
                w1f[mt][kt] = __builtin_bit_cast(half8v, gw1[(mt * 2 + kt) * 64 + lane]);
                PIN(w1f[mt][kt]);
            }
        const uint4* gw2 = (const uint4*)w2_frag;
        #pragma unroll
        for (int mt2 = 0; mt2 < 4; mt2++)
            #pragma unroll
            for (int kt = 0; kt < 4; kt++) {
                w2f[mt2][kt] = __builtin_bit_cast(half8v, gw2[(mt2 * 4 + kt) * 64 + lane]);
                PIN(w2f[mt2][kt]);
            }
        #pragma unroll
        for (int kt = 0; kt < 2; kt++) {
            w3f[kt] = *(const half8v*)(w3p + kt * 32 + lq * 8);
            PIN(w3f[kt]);
        }
    }
    f32x4 b2v[4];
    #pragma unroll
    for (int mt2 = 0; mt2 < 4; mt2++) {
        b2v[mt2] = *(const f32x4*)(b2 + mt2 * 16 + lq * 4);
        PIN(b2v[mt2]);
    }
    const float b3s = b3[0];
    f32x4 b3c = {b3s, b3s, b3s, b3s};

    // ---- j-side package: loaded once per wave (pinned) ----
    const int j = jbase + lr;
    half8v dstf0, dstf1;
    {
        const uint4* drow = (const uint4*)(dst_f16 + (size_t)j * 64);
        dstf0 = __builtin_bit_cast(half8v, drow[lq]);
        dstf1 = __builtin_bit_cast(half8v, drow[4 + lq]);
        PIN(dstf0); PIN(dstf1);
    }
    half2v b1pk[8][2];
    #pragma unroll
    for (int mt = 0; mt < 8; mt++) {
        uint2v bl = *(const uint2v*)(B1h + (size_t)j * 128 + mt * 16 + lq * 4);
        b1pk[mt][0] = __builtin_bit_cast(half2v, bl[0]);
        b1pk[mt][1] = __builtin_bit_cast(half2v, bl[1]);
        PIN(b1pk[mt][0]); PIN(b1pk[mt][1]);
    }

    // ---- chunk loop: one i per chunk, 16 j ----
    half8v s0, s1;
    f32x4 acc1[8];
    {
        const uint4* srow = (const uint4*)(src_f16 + (size_t)ibase * 64);
        s0 = __builtin_bit_cast(half8v, srow[lq]);
        s1 = __builtin_bit_cast(half8v, srow[4 + lq]);
        #pragma unroll
        for (int mt = 0; mt < 8; mt++)
            acc1[mt] = *(const f32x4*)(A1 + (size_t)ibase * 128 + mt * 16 + lq * 4);
    }

    for (int cc = 0; cc < 16; cc++) {
        const int i = ibase + cc;
        const half8v c0 = s0 * dstf0;
        const half8v c1 = s1 * dstf1;

        // GEMM1 phase A (mt 0..3)
        #pragma unroll
        for (int mt = 0; mt < 4; mt++) {
            acc1[mt] = __builtin_amdgcn_mfma_f32_16x16x32_f16(w1f[mt][0], c0, acc1[mt], 0, 0, 0);
            acc1[mt] = __builtin_amdgcn_mfma_f32_16x16x32_f16(w1f[mt][1], c1, acc1[mt], 0, 0, 0);
        }
        // epilogue A -> P[0..7]
        unsigned P[16];
        #pragma unroll
        for (int mt = 0; mt < 4; mt++) {
            half2v p0 = cvt_pk(acc1[mt][0], acc1[mt][1]) + b1pk[mt][0];
            half2v p1 = cvt_pk(acc1[mt][2], acc1[mt][3]) + b1pk[mt][1];
            P[mt * 2 + 0] = __builtin_bit_cast(unsigned, pkmax0(p0));
            P[mt * 2 + 1] = __builtin_bit_cast(unsigned, pkmax0(p1));
        }
        // GEMM2 kt0, kt1 (C-init = b2)
        f32x4 acc2[4];
        {
            uint4 hb = {P[0], P[1], P[2], P[3]};
            half8v hf = __builtin_bit_cast(half8v, hb);
            #pragma unroll
            for (int mt2 = 0; mt2 < 4; mt2++)
                acc2[mt2] = __builtin_amdgcn_mfma_f32_16x16x32_f16(w2f[mt2][0], hf, b2v[mt2], 0, 0, 0);
        }
        {
            uint4 hb = {P[4], P[5], P[6], P[7]};
            half8v hf = __builtin_bit_cast(half8v, hb);
            #pragma unroll
            for (int mt2 = 0; mt2 < 4; mt2++)
                acc2[mt2] = __builtin_amdgcn_mfma_f32_16x16x32_f16(w2f[mt2][1], hf, acc2[mt2], 0, 0, 0);
        }
        // GEMM1 phase B (mt 4..7)
        #pragma unroll
        for (int mt = 4; mt < 8; mt++) {
            acc1[mt] = __builtin_amdgcn_mfma_f32_16x16x32_f16(w1f[mt][0], c0, acc1[mt], 0, 0, 0);
            acc1[mt] = __builtin_amdgcn_mfma_f32_16x16x32_f16(w1f[mt][1], c1, acc1[mt], 0, 0, 0);
        }
        // epilogue B -> P[8..15]
        #pragma unroll
        for (int mt = 4; mt < 8; mt++) {
            half2v p0 = cvt_pk(acc1[mt][0], acc1[mt][1]) + b1pk[mt][0];
            half2v p1 = cvt_pk(acc1[mt][2], acc1[mt][3]) + b1pk[mt][1];
            P[mt * 2 + 0] = __builtin_bit_cast(unsigned, pkmax0(p0));
            P[mt * 2 + 1] = __builtin_bit_cast(unsigned, pkmax0(p1));
        }
        // prefetch next chunk's src + A1 into the now-dead s/acc1 regs
        if (cc < 15) {
            const int inext = i + 1;
            const uint4* srow = (const uint4*)(src_f16 + (size_t)inext * 64);
            s0 = __builtin_bit_cast(half8v, srow[lq]);
            s1 = __builtin_bit_cast(half8v, srow[4 + lq]);
            #pragma unroll
            for (int mt = 0; mt < 8; mt++)
                acc1[mt] = *(const f32x4*)(A1 + (size_t)inext * 128 + mt * 16 + lq * 4);
        }
        // GEMM2 kt2, kt3
        {
            uint4 hb = {P[8], P[9], P[10], P[11]};
            half8v hf = __builtin_bit_cast(half8v, hb);
            #pragma unroll
            for (int mt2 = 0; mt2 < 4; mt2++)
                acc2[mt2] = __builtin_amdgcn_mfma_f32_16x16x32_f16(w2f[mt2][2], hf, acc2[mt2], 0, 0, 0);
        }
        {
            uint4 hb = {P[12], P[13], P[14], P[15]};
            half8v hf = __builtin_bit_cast(half8v, hb);
            #pragma unroll
            for (int mt2 = 0; mt2 < 4; mt2++)
                acc2[mt2] = __builtin_amdgcn_mfma_f32_16x16x32_f16(w2f[mt2][3], hf, acc2[mt2], 0, 0, 0);
        }
        // GEMM3: relu(h2) -> f16 (sigma order), 2 MFMAs, C-init = b3
        unsigned P2[8];
        #pragma unroll
        for (int mt2 = 0; mt2 < 4; mt2++) {
            P2[mt2 * 2 + 0] = __builtin_bit_cast(unsigned, pkmax0(cvt_pk(acc2[mt2][0], acc2[mt2][1])));
            P2[mt2 * 2 + 1] = __builtin_bit_cast(unsigned, pkmax0(cvt_pk(acc2[mt2][2], acc2[mt2][3])));
        }
        uint4 h20 = {P2[0], P2[1], P2[2], P2[3]};
        uint4 h21 = {P2[4], P2[5], P2[6], P2[7]};
        f32x4 acc3 = __builtin_amdgcn_mfma_f32_16x16x32_f16(
            w3f[0], __builtin_bit_cast(half8v, h20), b3c, 0, 0, 0);
        acc3 = __builtin_amdgcn_mfma_f32_16x16x32_f16(
            w3f[1], __builtin_bit_cast(half8v, h21), acc3, 0, 0, 0);
        if (lane < 16)
            out[(size_t)i * 1024 + jbase + lane] = acc3[0];
    }
}

// ---------------------------------------------------------------------------
extern "C" void kernel_launch(void* const* d_in, const int* in_sizes, int n_in,
                              void* d_out, int out_size, void* d_ws, size_t ws_size,
                              hipStream_t stream) {
    (void)in_sizes; (void)n_in; (void)out_size; (void)ws_size;
    const float* node   = (const float*)d_in[0];
    const float* w_src  = (const float*)d_in[1];
    const float* b_src  = (const float*)d_in[2];
    const float* g_src  = (const float*)d_in[3];
    const float* be_src = (const float*)d_in[4];
    const float* w_dst  = (const float*)d_in[5];
    const float* b_dst  = (const float*)d_in[6];
    const float* g_dst  = (const float*)d_in[7];
    const float* be_dst = (const float*)d_in[8];
    const float* w1     = (const float*)d_in[9];
    const float* b1     = (const float*)d_in[10];
    const float* w2     = (const float*)d_in[11];
    const float* b2     = (const float*)d_in[12];
    const float* w3     = (const float*)d_in[13];
    const float* b3     = (const float*)d_in[14];

    char* ws = (char*)d_ws;
    unsigned short* src_f16  = (unsigned short*)(ws);
    unsigned short* dst_f16  = (unsigned short*)(ws + 131072);
    float*          A1       = (float*)(ws + 262144);
    unsigned short* B1h      = (unsigned short*)(ws + 786432);
    unsigned short* w1c_frag = (unsigned short*)(ws + 1310720);
    unsigned short* w2_frag  = (unsigned short*)(ws + 1327104);
    unsigned short* w3p      = (unsigned short*)(ws + 1343488);

    hipLaunchKernelGGL(proj_kernel, dim3(512), dim3(256), 0, stream,
                       node, w_src, b_src, g_src, be_src, w_dst, b_dst, g_dst, be_dst,
                       w1, b1, w2, w3, src_f16, dst_f16, A1, B1h,
                       w1c_frag, w2_frag, w3p);
    hipLaunchKernelGGL(pair_kernel, dim3(32, 32), dim3(256), 0, stream,
                       src_f16, dst_f16, A1, B1h, w1c_frag, w2_frag, w3p, b2, b3,
                       (float*)d_out);
}

// Round 8
// 42.405 us; speedup vs baseline: 3.1044x; 1.3482x over previous
//
#include <hip/hip_runtime.h>

typedef _Float16 half2v __attribute__((ext_vector_type(2)));
typedef _Float16 half8v __attribute__((ext_vector_type(8)));
typedef float f32x4 __attribute__((ext_vector_type(4)));
typedef unsigned uint2v __attribute__((ext_vector_type(2)));

__device__ inline half2v cvt_pk(float a, float b) {
    return __builtin_bit_cast(half2v, __builtin_amdgcn_cvt_pkrtz(a, b));
}
__device__ inline half2v pkmax0(half2v x) {
    half2v r;
    asm("v_pk_max_f16 %0, %1, 0" : "=v"(r) : "v"(x));
    return r;
}
__device__ inline unsigned short f16bits(float f) {
    _Float16 h = (_Float16)f;
    return __builtin_bit_cast(unsigned short, h);
}
__device__ inline unsigned packf16(float a, float b) {
    return (unsigned)f16bits(a) | ((unsigned)f16bits(b) << 16);
}
__device__ inline float lo16(unsigned u) {
    return (float)__builtin_bit_cast(_Float16, (unsigned short)(u & 0xffffu));
}
__device__ inline float hi16(unsigned u) {
    return (float)__builtin_bit_cast(_Float16, (unsigned short)(u >> 16));
}

// ---------------------------------------------------------------------------
// K0: src/dst = relu(LN(node @ W^T + b)) -> f16; A1 = src@W1a^T + b1 (f32);
//     B1h = dst@W1b^T (f16). W and the w1 k-slice staged in LDS as f16 with
//     conflict-free strides. Blocks 0..7 pack w1c/w2 into MFMA A-frag order
//     (w2 with sigma perm); block 8 packs w3 with sigma.
//       sigma(kt, lq*8+e) = (2*kt + (e>>2))*16 + lq*4 + (e&3)
// ---------------------------------------------------------------------------
__global__ __launch_bounds__(256) void proj_kernel(
    const float* __restrict__ node,
    const float* __restrict__ w_src, const float* __restrict__ b_src,
    const float* __restrict__ g_src, const float* __restrict__ be_src,
    const float* __restrict__ w_dst, const float* __restrict__ b_dst,
    const float* __restrict__ g_dst, const float* __restrict__ be_dst,
    const float* __restrict__ w1, const float* __restrict__ b1,
    const float* __restrict__ w2, const float* __restrict__ w3,
    unsigned short* __restrict__ src_f16, unsigned short* __restrict__ dst_f16,
    float* __restrict__ A1, unsigned short* __restrict__ B1h,
    unsigned short* __restrict__ w1c_frag, unsigned short* __restrict__ w2_frag,
    unsigned short* __restrict__ w3p)
{
    __shared__ unsigned sWh[64 * 65];    // W(kind) as packed f16 pairs, stride 65
    __shared__ unsigned sw1h[128 * 33];  // w1[:,koff:koff+64] f16 pairs, stride 33
    __shared__ float snode[4][128];
    __shared__ float sy[4][64];

    const int tid = threadIdx.x;
    const int wloc = tid >> 6;
    const int lane = tid & 63;
    const int gw = blockIdx.x * 4 + wloc;     // 0..2047
    const int row = gw & 1023;
    const int kind = gw >> 10;                // uniform per block

    const float* W  = kind ? w_dst  : w_src;
    const float* Bv = kind ? b_dst  : b_src;
    const float* G  = kind ? g_dst  : g_src;
    const float* BE = kind ? be_dst : be_src;
    const int koff = kind * 64;

    // ---- stage W (64x128) and w1-slice (128x64) as f16 pairs, coalesced ----
    #pragma unroll
    for (int u = 0; u < 16; u++) {
        int w = u * 256 + tid;                // 0..4095
        int r = w >> 6, c2 = w & 63;
        float2 v = *(const float2*)(W + r * 128 + c2 * 2);
        sWh[r * 65 + c2] = packf16(v.x, v.y);
    }
    #pragma unroll
    for (int u = 0; u < 16; u++) {
        int w = u * 256 + tid;                // 0..4095
        int r = w >> 5, c2 = w & 31;
        float2 v = *(const float2*)(w1 + (size_t)r * 192 + koff + c2 * 2);
        sw1h[r * 33 + c2] = packf16(v.x, v.y);
    }
    snode[wloc][lane]      = node[row * 128 + lane];
    snode[wloc][lane + 64] = node[row * 128 + 64 + lane];
    __syncthreads();

    // ---- projection dot: acc = b + node . W[lane,:] ----
    float acc = Bv[lane];
    #pragma unroll 8
    for (int k2 = 0; k2 < 64; k2++) {
        unsigned wp = sWh[lane * 65 + k2];
        float2 nv = *(const float2*)&snode[wloc][2 * k2];
        acc += nv.x * lo16(wp) + nv.y * hi16(wp);
    }

    // LayerNorm over 64 lanes
    float s = acc;
    #pragma unroll
    for (int off = 32; off >= 1; off >>= 1) s += __shfl_xor(s, off);
    float mean = s * (1.0f / 64.0f);
    float d = acc - mean;
    float ss = d * d;
    #pragma unroll
    for (int off = 32; off >= 1; off >>= 1) ss += __shfl_xor(ss, off);
    float rstd = rsqrtf(ss * (1.0f / 64.0f) + 1e-5f);
    float y = fmaxf(d * rstd * G[lane] + BE[lane], 0.0f);

    unsigned short* obf = kind ? dst_f16 : src_f16;
    obf[row * 64 + lane] = f16bits(y);

    sy[wloc][lane] = y;
    __builtin_amdgcn_s_waitcnt(0);   // within-wave LDS RAW

    // ---- A1/B1 projection: a{0,1} = y . w1[m, koff:koff+64] ----
    float a0 = kind ? 0.0f : b1[lane];
    float a1 = kind ? 0.0f : b1[lane + 64];
    #pragma unroll 8
    for (int k2 = 0; k2 < 32; k2++) {
        float2 yv = *(const float2*)&sy[wloc][2 * k2];
        unsigned wa = sw1h[lane * 33 + k2];
        unsigned wb = sw1h[(lane + 64) * 33 + k2];
        a0 += yv.x * lo16(wa) + yv.y * hi16(wa);
        a1 += yv.x * lo16(wb) + yv.y * hi16(wb);
    }
    if (kind == 0) {
        A1[row * 128 + lane] = a0;
        A1[row * 128 + lane + 64] = a1;
    } else {
        B1h[row * 128 + lane] = f16bits(a0);
        B1h[row * 128 + lane + 64] = f16bits(a1);
    }

    // ---- weight packing (blocks 0..8 only) ----
    if (blockIdx.x < 8) {
        int t = blockIdx.x * 256 + threadIdx.x;   // 0..2047
        int which = t >> 10;
        int idx = t & 1023;                       // f*64 + l
        int f = idx >> 6, l = idx & 63;
        int lqq = l >> 4, lrr = l & 15;
        if (which == 0) {
            int mt = f >> 1, kt = f & 1;          // A-frag of W1c
            #pragma unroll
            for (int e = 0; e < 8; e++)
                w1c_frag[idx * 8 + e] =
                    f16bits(w1[(size_t)(mt * 16 + lrr) * 192 + 128 + kt * 32 + lqq * 8 + e]);
        } else {
            int mt2 = f >> 2, kt2 = f & 3;        // A-frag of W2 with sigma perm
            #pragma unroll
            for (int e = 0; e < 8; e++) {
                int col = (2 * kt2 + (e >> 2)) * 16 + lqq * 4 + (e & 3);
                w2_frag[idx * 8 + e] =
                    f16bits(w2[(size_t)(mt2 * 16 + lrr) * 128 + col]);
            }
        }
    } else if (blockIdx.x == 8 && threadIdx.x < 64) {
        int l = threadIdx.x;
        int kt = l >> 5, rem = l & 31, lqq = rem >> 3, ee = rem & 7;
        w3p[l] = f16bits(w3[(2 * kt + (ee >> 2)) * 16 + lqq * 4 + (ee & 3)]);
    }
}

// ---------------------------------------------------------------------------
// K1: pairwise MLP, all-register MFMA weights, LDS-resident i-side operands.
// Block = 32 i x 32 j, 4 waves; wave (wv&1, wv>>1) owns 16 i x 16 j.
// Per block: stage A1 tile (32x128 f32) + src tile (32x64 f16) in LDS once.
// Chunk = (one i, 16 j = lr): C-init and src come from LDS (broadcast reads,
// conflict-free), GEMM1 -> epilogue(+B1h,relu,pack) -> GEMM2(sigma-W2, own-reg
// B-frags) -> GEMM3(sigma-w3) -> store.
// ---------------------------------------------------------------------------
__global__ __launch_bounds__(256, 2) void pair_kernel(
    const unsigned short* __restrict__ src_f16, const unsigned short* __restrict__ dst_f16,
    const float* __restrict__ A1, const unsigned short* __restrict__ B1h,
    const unsigned short* __restrict__ w1c_frag, const unsigned short* __restrict__ w2_frag,
    const unsigned short* __restrict__ w3p, const float* __restrict__ b2,
    const float* __restrict__ b3, float* __restrict__ out)
{
    __shared__ __align__(16) float sA1[32][128];          // 16 KB
    __shared__ __align__(16) unsigned short sSrc[32][64]; // 4 KB

    const int tid = threadIdx.x;
    const int wv = tid >> 6;
    const int lane = tid & 63;
    const int lq = lane >> 4, lr = lane & 15;
    const int i0 = blockIdx.y * 32, j0 = blockIdx.x * 32;
    const int ibase = (wv & 1) * 16;
    const int jbase = j0 + (wv >> 1) * 16;

    // ---- cooperative stage of i-side tiles (coalesced b128) ----
    #pragma unroll
    for (int u = 0; u < 4; u++) {
        int idx = u * 256 + tid;              // 0..1023
        int r = idx >> 5, c = (idx & 31) * 4;
        *(f32x4*)&sA1[r][c] = *(const f32x4*)(A1 + (size_t)(i0 + r) * 128 + c);
    }
    {
        int r = tid >> 3, c = (tid & 7) * 8;
        *(uint4*)&sSrc[r][c] = *(const uint4*)(src_f16 + (size_t)(i0 + r) * 64 + c);
    }

    // ---- weight fragments from global (coalesced b128, L2-hot) ----
    half8v w1f[8][2], w2f[4][4], w3f[2];
    {
        const uint4* gw1 = (const uint4*)w1c_frag;
        #pragma unroll
        for (int mt = 0; mt < 8; mt++)
            #pragma unroll
            for (int kt = 0; kt < 2; kt++)
                w1f[mt][kt] = __builtin_bit_cast(half8v, gw1[(mt * 2 + kt) * 64 + lane]);
        const uint4* gw2 = (const uint4*)w2_frag;
        #pragma unroll
        for (int mt2 = 0; mt2 < 4; mt2++)
            #pragma unroll
            for (int kt = 0; kt < 4; kt++)
                w2f[mt2][kt] = __builtin_bit_cast(half8v, gw2[(mt2 * 4 + kt) * 64 + lane]);
        #pragma unroll
        for (int kt = 0; kt < 2; kt++)
            w3f[kt] = *(const half8v*)(w3p + kt * 32 + lq * 8);
    }
    f32x4 b2v[4];
    #pragma unroll
    for (int mt2 = 0; mt2 < 4; mt2++)
        b2v[mt2] = *(const f32x4*)(b2 + mt2 * 16 + lq * 4);
    const float b3s = b3[0];
    const f32x4 b3c = {b3s, b3s, b3s, b3s};

    // ---- j-side package: loaded once per wave ----
    const int j = jbase + lr;
    half8v dstf0, dstf1;
    {
        const uint4* drow = (const uint4*)(dst_f16 + (size_t)j * 64);
        dstf0 = __builtin_bit_cast(half8v, drow[lq]);
        dstf1 = __builtin_bit_cast(half8v, drow[4 + lq]);
    }
    half2v b1pk[8][2];
    #pragma unroll
    for (int mt = 0; mt < 8; mt++) {
        uint2v bl = *(const uint2v*)(B1h + (size_t)j * 128 + mt * 16 + lq * 4);
        b1pk[mt][0] = __builtin_bit_cast(half2v, bl[0]);
        b1pk[mt][1] = __builtin_bit_cast(half2v, bl[1]);
    }

    __syncthreads();

    // ---- 16 chunks: one i each; operands from LDS ----
    for (int cc = 0; cc < 16; cc++) {
        const int i_loc = ibase + cc;
        const int i = i0 + i_loc;
        const half8v s0 = *(const half8v*)&sSrc[i_loc][lq * 8];
        const half8v s1 = *(const half8v*)&sSrc[i_loc][32 + lq * 8];
        f32x4 acc1[8];
        #pragma unroll
        for (int mt = 0; mt < 8; mt++)
            acc1[mt] = *(const f32x4*)&sA1[i_loc][mt * 16 + lq * 4];
        // cross features
        const half8v c0 = s0 * dstf0;
        const half8v c1 = s1 * dstf1;
        // GEMM1
        #pragma unroll
        for (int mt = 0; mt < 8; mt++) {
            acc1[mt] = __builtin_amdgcn_mfma_f32_16x16x32_f16(w1f[mt][0], c0, acc1[mt], 0, 0, 0);
            acc1[mt] = __builtin_amdgcn_mfma_f32_16x16x32_f16(w1f[mt][1], c1, acc1[mt], 0, 0, 0);
        }
        // epilogue: +B1, relu, pack f16 into P
        unsigned P[16];
        #pragma unroll
        for (int mt = 0; mt < 8; mt++) {
            half2v p0 = cvt_pk(acc1[mt][0], acc1[mt][1]) + b1pk[mt][0];
            half2v p1 = cvt_pk(acc1[mt][2], acc1[mt][3]) + b1pk[mt][1];
            P[mt * 2 + 0] = __builtin_bit_cast(unsigned, pkmax0(p0));
            P[mt * 2 + 1] = __builtin_bit_cast(unsigned, pkmax0(p1));
        }
        // GEMM2: sigma-W2; B-frag = own P regs; C-init = b2
        f32x4 acc2[4];
        {
            uint4 hb = {P[0], P[1], P[2], P[3]};
            half8v hf = __builtin_bit_cast(half8v, hb);
            #pragma unroll
            for (int mt2 = 0; mt2 < 4; mt2++)
                acc2[mt2] = __builtin_amdgcn_mfma_f32_16x16x32_f16(w2f[mt2][0], hf, b2v[mt2], 0, 0, 0);
        }
        #pragma unroll
        for (int kt = 1; kt < 4; kt++) {
            uint4 hb = {P[4 * kt], P[4 * kt + 1], P[4 * kt + 2], P[4 * kt + 3]};
            half8v hf = __builtin_bit_cast(half8v, hb);
            #pragma unroll
            for (int mt2 = 0; mt2 < 4; mt2++)
                acc2[mt2] = __builtin_amdgcn_mfma_f32_16x16x32_f16(w2f[mt2][kt], hf, acc2[mt2], 0, 0, 0);
        }
        // GEMM3: relu(h2) -> f16 (sigma order), 2 MFMAs, C-init = b3
        unsigned P2[8];
        #pragma unroll
        for (int mt2 = 0; mt2 < 4; mt2++) {
            P2[mt2 * 2 + 0] = __builtin_bit_cast(unsigned, pkmax0(cvt_pk(acc2[mt2][0], acc2[mt2][1])));
            P2[mt2 * 2 + 1] = __builtin_bit_cast(unsigned, pkmax0(cvt_pk(acc2[mt2][2], acc2[mt2][3])));
        }
        uint4 h20 = {P2[0], P2[1], P2[2], P2[3]};
        uint4 h21 = {P2[4], P2[5], P2[6], P2[7]};
        f32x4 acc3 = __builtin_amdgcn_mfma_f32_16x16x32_f16(
            w3f[0], __builtin_bit_cast(half8v, h20), b3c, 0, 0, 0);
        acc3 = __builtin_amdgcn_mfma_f32_16x16x32_f16(
            w3f[1], __builtin_bit_cast(half8v, h21), acc3, 0, 0, 0);
        if (lane < 16)
            out[(size_t)i * 1024 + jbase + lane] = acc3[0];
    }
}

// ---------------------------------------------------------------------------
extern "C" void kernel_launch(void* const* d_in, const int* in_sizes, int n_in,
                              void* d_out, int out_size, void* d_ws, size_t ws_size,
                              hipStream_t stream) {
    (void)in_sizes; (void)n_in; (void)out_size; (void)ws_size;
    const float* node   = (const float*)d_in[0];
    const float* w_src  = (const float*)d_in[1];
    const float* b_src  = (const float*)d_in[2];
    const float* g_src  = (const float*)d_in[3];
    const float* be_src = (const float*)d_in[4];
    const float* w_dst  = (const float*)d_in[5];
    const float* b_dst  = (const float*)d_in[6];
    const float* g_dst  = (const float*)d_in[7];
    const float* be_dst = (const float*)d_in[8];
    const float* w1     = (const float*)d_in[9];
    const float* b1     = (const float*)d_in[10];
    const float* w2     = (const float*)d_in[11];
    const float* b2     = (const float*)d_in[12];
    const float* w3     = (const float*)d_in[13];
    const float* b3     = (const float*)d_in[14];

    char* ws = (char*)d_ws;
    unsigned short* src_f16  = (unsigned short*)(ws);
    unsigned short* dst_f16  = (unsigned short*)(ws + 131072);
    float*          A1       = (float*)(ws + 262144);
    unsigned short* B1h      = (unsigned short*)(ws + 786432);
    unsigned short* w1c_frag = (unsigned short*)(ws + 1310720);
    unsigned short* w2_frag  = (unsigned short*)(ws + 1327104);
    unsigned short* w3p      = (unsigned short*)(ws + 1343488);

    hipLaunchKernelGGL(proj_kernel, dim3(512), dim3(256), 0, stream,
                       node, w_src, b_src, g_src, be_src, w_dst, b_dst, g_dst, be_dst,
                       w1, b1, w2, w3, src_f16, dst_f16, A1, B1h,
                       w1c_frag, w2_frag, w3p);
    hipLaunchKernelGGL(pair_kernel, dim3(32, 32), dim3(256), 0, stream,
                       src_f16, dst_f16, A1, B1h, w1c_frag, w2_frag, w3p, b2, b3,
                       (float*)d_out);
}